// Round 12
// baseline (1836.056 us; speedup 1.0000x reference)
//
#include <hip/hip_runtime.h>
#include <hip/hip_bf16.h>

#define N_NODES  50000
#define N_HEDGES 25000
#define E_NN     800000
#define E_HH     400000
#define E_INC    200000
#define D        128

// ---- bucket geometry (64 receivers per bucket) ----
#define NB_NN   782
#define NB_H2N  782
#define NB_HH   391
#define NB_N2H  391
#define NB_TOT  2346
#define NB_MAX  782

#define BC_NN   0
#define BC_H2N  782
#define BC_HH   1564
#define BC_N2H  1955

#define REC_NN  0
#define REC_H2N 800000
#define REC_HH  1000000
#define REC_N2H 1400000

// hist/passA block layout: 2048 edges per block
#define HB_NN0   0
#define HB_H2N0  391
#define HB_HH0   489
#define HB_N2H0  685
#define HB_TOT   783
#define HIST_GRID (HB_TOT + 256)   // + swizzleW blocks

// ---------------------------------------------------------------------------
// histsw: bucket-level histogram of all 4 edge sets + fused weight swizzle.
// Swizzle layout: out[cgrp*516 + k4*16 + ci*4 + kk], c=cgrp*4+ci, k=k4*4+kk
// ---------------------------------------------------------------------------
__global__ __launch_bounds__(256) void histsw(
    const int* __restrict__ rNN, const int* __restrict__ rH2N,
    const int* __restrict__ rHH, const int* __restrict__ rN2H,
    int* __restrict__ bcnt,
    const float* __restrict__ w0, const float* __restrict__ w1,
    const float* __restrict__ w2, const float* __restrict__ w3,
    float* __restrict__ Wz) {
  int b = blockIdx.x;
  if (b >= HB_TOT) {   // weight swizzle blocks
    int id = (b - HB_TOT) * 256 + threadIdx.x;   // 0..65535
    int m = id >> 14, r = id & 16383;
    const float* w = (m == 0) ? w0 : (m == 1) ? w1 : (m == 2) ? w2 : w3;
    int c = r >> 7, k = r & 127;
    Wz[m * 16512 + (c >> 2) * 516 + (k >> 2) * 16 + (c & 3) * 4 + (k & 3)] = w[r];
    return;
  }
  const int* rcv; int E, base, bc;
  if (b < HB_H2N0)      { rcv = rNN;  E = E_NN;  base = HB_NN0;  bc = BC_NN; }
  else if (b < HB_HH0)  { rcv = rH2N; E = E_INC; base = HB_H2N0; bc = BC_H2N; }
  else if (b < HB_N2H0) { rcv = rHH;  E = E_HH;  base = HB_HH0;  bc = BC_HH; }
  else                  { rcv = rN2H; E = E_INC; base = HB_N2H0; bc = BC_N2H; }
  int e0 = (b - base) * 2048 + threadIdx.x;
#pragma unroll
  for (int j = 0; j < 8; ++j) {
    int e = e0 + j * 256;
    if (e < E) atomicAdd(&bcnt[bc + (rcv[e] >> 6)], 1);
  }
}

// ---------------------------------------------------------------------------
// kscan: one block; exclusive scan of each set's bucket counters.
// Writes boffs* (nb+1 entries, relative to the set's record base) and bcur.
// ---------------------------------------------------------------------------
__global__ __launch_bounds__(1024) void kscan(
    const int* __restrict__ bcnt, int* __restrict__ bcur,
    int* __restrict__ oNN, int* __restrict__ oH2N,
    int* __restrict__ oHH, int* __restrict__ oN2H) {
  __shared__ int wsum[16];
  int t = threadIdx.x, lane = t & 63, wid = t >> 6;
  for (int s = 0; s < 4; ++s) {
    int nb = (s < 2) ? 782 : 391;
    int bc = (s == 0) ? BC_NN : (s == 1) ? BC_H2N : (s == 2) ? BC_HH : BC_N2H;
    int* o = (s == 0) ? oNN : (s == 1) ? oH2N : (s == 2) ? oHH : oN2H;
    int v = (t < nb) ? bcnt[bc + t] : 0;
    int inc = v;
#pragma unroll
    for (int off = 1; off < 64; off <<= 1) {
      int tv = __shfl_up(inc, off, 64);
      if (lane >= off) inc += tv;
    }
    if (lane == 63) wsum[wid] = inc;
    __syncthreads();
    if (t == 0) {
      int run = 0;
      for (int w = 0; w < 16; ++w) { int x = wsum[w]; wsum[w] = run; run += x; }
    }
    __syncthreads();
    int ex = wsum[wid] + inc - v;
    if (t < nb) { o[t] = ex; bcur[bc + t] = ex; }
    if (t == nb - 1) o[nb] = ex + v;
    __syncthreads();   // protect wsum reuse
  }
}

// ---------------------------------------------------------------------------
// passA: bucket partition. Writes packed records {snd | (rcv&63)<<20, conv}
// in bucket-grouped runs (block-local LDS histogram + one global atomic per
// touched bucket).
// ---------------------------------------------------------------------------
__global__ __launch_bounds__(256) void passA(
    const int* __restrict__ sNN, const int* __restrict__ rNN, const float* __restrict__ vNN,
    const int* __restrict__ sH2N, const int* __restrict__ rH2N, const float* __restrict__ vH2N,
    const int* __restrict__ sHH, const int* __restrict__ rHH, const float* __restrict__ vHH,
    const int* __restrict__ sN2H, const int* __restrict__ rN2H, const float* __restrict__ vN2H,
    int* __restrict__ bcur, int2* __restrict__ rec) {
  __shared__ int hist[NB_MAX];
  __shared__ int gbase[NB_MAX];
  __shared__ int lcur[NB_MAX];
  int b = blockIdx.x;
  const int* snd; const int* rcv; const float* conv;
  int E, base, bcoff, recoff, NB;
  if (b < HB_H2N0)      { snd=sNN;  rcv=rNN;  conv=vNN;  E=E_NN;  base=HB_NN0;  bcoff=BC_NN;  recoff=REC_NN;  NB=NB_NN; }
  else if (b < HB_HH0)  { snd=sH2N; rcv=rH2N; conv=vH2N; E=E_INC; base=HB_H2N0; bcoff=BC_H2N; recoff=REC_H2N; NB=NB_H2N; }
  else if (b < HB_N2H0) { snd=sHH;  rcv=rHH;  conv=vHH;  E=E_HH;  base=HB_HH0;  bcoff=BC_HH;  recoff=REC_HH;  NB=NB_HH; }
  else                  { snd=sN2H; rcv=rN2H; conv=vN2H; E=E_INC; base=HB_N2H0; bcoff=BC_N2H; recoff=REC_N2H; NB=NB_N2H; }
  int t = threadIdx.x;
  int estart = (b - base) * 2048;

  int rv[8]; int sd[8]; float cv[8]; int bk[8]; bool ok[8];
#pragma unroll
  for (int j = 0; j < 8; ++j) {
    int e = estart + t + j * 256;
    ok[j] = e < E;
    int r = ok[j] ? rcv[e] : 0;
    rv[j] = r;
    bk[j] = r >> 6;
    sd[j] = ok[j] ? snd[e] : 0;
    cv[j] = ok[j] ? conv[e] : 0.f;
  }
  for (int i = t; i < NB; i += 256) hist[i] = 0;
  __syncthreads();
#pragma unroll
  for (int j = 0; j < 8; ++j) if (ok[j]) atomicAdd(&hist[bk[j]], 1);
  __syncthreads();
  for (int i = t; i < NB; i += 256) {
    int h = hist[i];
    gbase[i] = h ? atomicAdd(&bcur[bcoff + i], h) : 0;
    lcur[i] = 0;
  }
  __syncthreads();
#pragma unroll
  for (int j = 0; j < 8; ++j) if (ok[j]) {
    int rk = atomicAdd(&lcur[bk[j]], 1);
    int g = recoff + gbase[bk[j]] + rk;
    rec[g] = make_int2(sd[j] | ((rv[j] & 63) << 20), __float_as_int(cv[j]));
  }
}

// ---------------------------------------------------------------------------
// lin2: two independent Y = X @ W^T + b GEMMs in one launch.
// Block x: [0,nb1) -> problem 1 rows, [nb1,..) -> problem 2. y: col half.
// ---------------------------------------------------------------------------
__global__ __launch_bounds__(256) void lin2(
    const float* __restrict__ X1, const float* __restrict__ Wz1,
    const float* __restrict__ b1, float* __restrict__ Y1, int n1, int nb1,
    const float* __restrict__ X2, const float* __restrict__ Wz2,
    const float* __restrict__ b2, float* __restrict__ Y2, int n2) {
  __shared__ float Ws[16 * 516];
  __shared__ float Xs[64 * 132];
  int t = threadIdx.x;
  int bx = blockIdx.x;
  const float* X; const float* Wzp; const float* bias; float* Y; int n, r0;
  if (bx < nb1) { X = X1; Wzp = Wz1; bias = b1; Y = Y1; n = n1; r0 = bx * 64; }
  else          { X = X2; Wzp = Wz2; bias = b2; Y = Y2; n = n2; r0 = (bx - nb1) * 64; }
  int cb = blockIdx.y * 64;

  const float* wsrc = Wzp + blockIdx.y * (16 * 516);
  for (int i = t * 4; i < 16 * 516; i += 1024)
    *(float4*)(Ws + i) = *(const float4*)(wsrc + i);

  for (int q = t; q < 2048; q += 256) {
    int r = q >> 5, k4 = q & 31;
    float4 v = (r0 + r < n) ? *(const float4*)(X + (size_t)(r0 + r) * D + k4 * 4)
                            : make_float4(0.f, 0.f, 0.f, 0.f);
    *(float4*)(&Xs[r * 132 + k4 * 4]) = v;
  }
  __syncthreads();

  int tr = t >> 4, tc = t & 15;
  float acc[4][4] = {};
  const float* xbase = &Xs[tr * 4 * 132];
  const float* wbase = &Ws[tc * 516];

#pragma unroll 8
  for (int k4 = 0; k4 < 32; ++k4) {
    float4 xv[4], wv[4];
#pragma unroll
    for (int i = 0; i < 4; ++i) xv[i] = *(const float4*)(xbase + i * 132 + k4 * 4);
#pragma unroll
    for (int j = 0; j < 4; ++j) wv[j] = *(const float4*)(wbase + k4 * 16 + j * 4);
#pragma unroll
    for (int i = 0; i < 4; ++i)
#pragma unroll
      for (int j = 0; j < 4; ++j)
        acc[i][j] += xv[i].x * wv[j].x + xv[i].y * wv[j].y +
                     xv[i].z * wv[j].z + xv[i].w * wv[j].w;
  }

  int c0 = cb + tc * 4;
  float4 bv = *(const float4*)(bias + c0);
#pragma unroll
  for (int i = 0; i < 4; ++i) {
    int r = r0 + tr * 4 + i;
    if (r < n) {
      float4 o;
      o.x = acc[i][0] + bv.x; o.y = acc[i][1] + bv.y;
      o.z = acc[i][2] + bv.z; o.w = acc[i][3] + bv.w;
      *(float4*)(Y + (size_t)r * D + c0) = o;
    }
  }
}

// ---------------------------------------------------------------------------
// gather_bucket: one block per 64-receiver bucket. Streams bucket-grouped
// records, accumulates conv * P[snd] into LDS via fp32 LDS atomics, then
// writes tanh(accA * accB) for the bucket's rows. No per-receiver CSR needed.
// ---------------------------------------------------------------------------
__global__ __launch_bounds__(256) void gather_bucket(
    const float* __restrict__ Pa, const int2* __restrict__ recA,
    const int* __restrict__ boffsA,
    const float* __restrict__ Pb, const int2* __restrict__ recB,
    const int* __restrict__ boffsB,
    float* __restrict__ out, int nrows) {
  __shared__ float accA[64 * 128];
  __shared__ float accB[64 * 128];
  int t = threadIdx.x;
  int bucket = blockIdx.x;
#pragma unroll
  for (int j = 0; j < 8; ++j)
    *(float4*)(accA + (t + j * 256) * 4) = make_float4(0.f, 0.f, 0.f, 0.f);
#pragma unroll
  for (int j = 0; j < 8; ++j)
    *(float4*)(accB + (t + j * 256) * 4) = make_float4(0.f, 0.f, 0.f, 0.f);
  __syncthreads();

  int wid = t >> 6, lane = t & 63;
  // ---- A side ----
  {
    int a0 = boffsA[bucket], a1 = boffsA[bucket + 1];
    int i = a0 + wid;
    for (; i + 28 < a1; i += 32) {
      int2 p[8]; float2 v[8];
#pragma unroll
      for (int j = 0; j < 8; ++j) p[j] = recA[i + 4 * j];
#pragma unroll
      for (int j = 0; j < 8; ++j)
        v[j] = *(const float2*)(Pa + (size_t)(p[j].x & 0xFFFFF) * D + lane * 2);
#pragma unroll
      for (int j = 0; j < 8; ++j) {
        float c = __int_as_float(p[j].y);
        int r6 = ((unsigned)p[j].x) >> 20;
        atomicAdd(&accA[r6 * 128 + lane * 2],     c * v[j].x);
        atomicAdd(&accA[r6 * 128 + lane * 2 + 1], c * v[j].y);
      }
    }
    for (; i < a1; i += 4) {
      int2 p = recA[i];
      float c = __int_as_float(p.y);
      float2 v = *(const float2*)(Pa + (size_t)(p.x & 0xFFFFF) * D + lane * 2);
      int r6 = ((unsigned)p.x) >> 20;
      atomicAdd(&accA[r6 * 128 + lane * 2],     c * v.x);
      atomicAdd(&accA[r6 * 128 + lane * 2 + 1], c * v.y);
    }
  }
  // ---- B side ----
  {
    int b0 = boffsB[bucket], b1 = boffsB[bucket + 1];
    int i = b0 + wid;
    for (; i + 28 < b1; i += 32) {
      int2 p[8]; float2 v[8];
#pragma unroll
      for (int j = 0; j < 8; ++j) p[j] = recB[i + 4 * j];
#pragma unroll
      for (int j = 0; j < 8; ++j)
        v[j] = *(const float2*)(Pb + (size_t)(p[j].x & 0xFFFFF) * D + lane * 2);
#pragma unroll
      for (int j = 0; j < 8; ++j) {
        float c = __int_as_float(p[j].y);
        int r6 = ((unsigned)p[j].x) >> 20;
        atomicAdd(&accB[r6 * 128 + lane * 2],     c * v[j].x);
        atomicAdd(&accB[r6 * 128 + lane * 2 + 1], c * v[j].y);
      }
    }
    for (; i < b1; i += 4) {
      int2 p = recB[i];
      float c = __int_as_float(p.y);
      float2 v = *(const float2*)(Pb + (size_t)(p.x & 0xFFFFF) * D + lane * 2);
      int r6 = ((unsigned)p.x) >> 20;
      atomicAdd(&accB[r6 * 128 + lane * 2],     c * v.x);
      atomicAdd(&accB[r6 * 128 + lane * 2 + 1], c * v.y);
    }
  }
  __syncthreads();

  // write: thread t -> row t>>2, 32-col quarter t&3
  int r = t >> 2, q = t & 3;
  int grow = bucket * 64 + r;
  if (grow < nrows) {
#pragma unroll
    for (int j = 0; j < 8; ++j) {
      int col = q * 32 + j * 4;
      float4 a = *(float4*)(accA + r * 128 + col);
      float4 b = *(float4*)(accB + r * 128 + col);
      float4 o;
      o.x = tanhf(a.x * b.x); o.y = tanhf(a.y * b.y);
      o.z = tanhf(a.z * b.z); o.w = tanhf(a.w * b.w);
      *(float4*)(out + (size_t)grow * D + col) = o;
    }
  }
}

extern "C" void kernel_launch(void* const* d_in, const int* in_sizes, int n_in,
                              void* d_out, int out_size, void* d_ws, size_t ws_size,
                              hipStream_t stream) {
  const float* node_features  = (const float*)d_in[0];
  const float* hedge_features = (const float*)d_in[1];
  const float* W_node_msg     = (const float*)d_in[2];
  const float* b_node_msg     = (const float*)d_in[3];
  const float* W_hedge_scale  = (const float*)d_in[4];
  const float* b_hedge_scale  = (const float*)d_in[5];
  const float* W_hedge_msg    = (const float*)d_in[6];
  const float* b_hedge_msg    = (const float*)d_in[7];
  const float* W_node_scale   = (const float*)d_in[8];
  const float* b_node_scale   = (const float*)d_in[9];
  const float* node_conv      = (const float*)d_in[10];
  const float* h2n_conv       = (const float*)d_in[11];
  const float* hedge_conv     = (const float*)d_in[12];
  const float* n2h_conv       = (const float*)d_in[13];
  const int*   node_snd       = (const int*)d_in[14];
  const int*   node_rcv       = (const int*)d_in[15];
  const int*   h2n_snd        = (const int*)d_in[16];
  const int*   h2n_rcv        = (const int*)d_in[17];
  const int*   hedge_snd      = (const int*)d_in[18];
  const int*   hedge_rcv      = (const int*)d_in[19];
  const int*   n2h_snd        = (const int*)d_in[20];
  const int*   n2h_rcv        = (const int*)d_in[21];

  float* out_node  = (float*)d_out;
  float* out_hedge = (float*)d_out + (size_t)N_NODES * D;

  // workspace layout
  float* ws = (float*)d_ws;
  float* Wz = ws;                                   // 66048 floats
  float* PA = ws + 66048;                           // 6.4M floats
  float* PB = PA + (size_t)N_NODES * D;             // 3.2M floats
  int2* rec = (int2*)(PB + (size_t)N_HEDGES * D);   // 1.6M int2
  int* bcnt = (int*)(rec + 1600000);                // 2346
  int* bcur = bcnt + NB_TOT;                        // 2346
  int* boffsNN  = bcur + NB_TOT;                    // 783
  int* boffsH2N = boffsNN + NB_NN + 1;              // 783
  int* boffsHH  = boffsH2N + NB_H2N + 1;            // 392
  int* boffsN2H = boffsHH + NB_HH + 1;              // 392

  // 0. zero bucket counters (tiny)
  hipMemsetAsync(bcnt, 0, (size_t)NB_TOT * sizeof(int), stream);

  // 1. bucket histogram + fused weight swizzle
  histsw<<<HIST_GRID, 256, 0, stream>>>(node_rcv, h2n_rcv, hedge_rcv, n2h_rcv,
                                        bcnt,
                                        W_node_msg, W_hedge_scale, W_hedge_msg,
                                        W_node_scale, Wz);
  // 2. bucket offsets
  kscan<<<1, 1024, 0, stream>>>(bcnt, bcur, boffsNN, boffsH2N, boffsHH, boffsN2H);
  // 3. bucket partition (packed records)
  passA<<<HB_TOT, 256, 0, stream>>>(
      node_snd, node_rcv, node_conv,
      h2n_snd, h2n_rcv, h2n_conv,
      hedge_snd, hedge_rcv, hedge_conv,
      n2h_snd, n2h_rcv, n2h_conv,
      bcur, rec);

  // ---- Stage 1: NodeConvolution ----
  lin2<<<dim3(NB_NN + NB_HH, 2), 256, 0, stream>>>(
      node_features, Wz + 0 * 16512, b_node_msg, PA, N_NODES, NB_NN,
      hedge_features, Wz + 1 * 16512, b_hedge_scale, PB, N_HEDGES);
  gather_bucket<<<NB_NN, 256, 0, stream>>>(
      PA, rec + REC_NN, boffsNN,
      PB, rec + REC_H2N, boffsH2N, out_node, N_NODES);

  // ---- Stage 2: HedgeConvolution ----
  lin2<<<dim3(NB_NN + NB_HH, 2), 256, 0, stream>>>(
      out_node, Wz + 3 * 16512, b_node_scale, PA, N_NODES, NB_NN,
      hedge_features, Wz + 2 * 16512, b_hedge_msg, PB, N_HEDGES);
  gather_bucket<<<NB_HH, 256, 0, stream>>>(
      PB, rec + REC_HH, boffsHH,
      PA, rec + REC_N2H, boffsN2H, out_hedge, N_HEDGES);
}